// Round 17
// baseline (397.923 us; speedup 1.0000x reference)
//
#include <hip/hip_runtime.h>
#include <hip/hip_fp16.h>

#define HH 352
#define WW 1216
#define HW (HH*WW)
#define NPIX (2*HW)      // 856064
#define NITER 18
#define PACK_BYTES ((size_t)NPIX * 64)

// conv MFMA geometry: 192-px tile, 3 blocks/CU  (round-12 verified: 93 us)
#define SEGW 192
#define NSEGC ((WW + SEGW - 1) / SEGW)    // 7
#define AROW_B 208                        // 104 bf16 per A row (96 used)
#define A_BYTES (SEGW * AROW_B)           // 39936
#define B_OFF A_BYTES
#define LDS_BYTES (A_BYTES + 32 * AROW_B) // 46592 -> 3 blocks/CU
#define OAROW_B 152                       // 38 f32 per OA row (27 used)

// prop LDS tile geometry: 4 rows x 256 cols per block
#define SEG 256
#define XHALO 6
#define YHALO 4
#define PROWS 4
#define TROWS (PROWS + 9)        // 13
#define TCOLS (SEG + 2*XHALO)    // 268
#define NSEG ((WW + SEG - 1) / SEG)   // 5

typedef __attribute__((ext_vector_type(8))) short short8;
typedef __attribute__((ext_vector_type(4))) float f32x4;

// manual RNE f32->bf16 twiddle: independent ALU work that overlaps load
// latency (round-15 lesson: intrinsic cast path was -40% despite fewer instrs)
__device__ __forceinline__ unsigned short f2bf(float f) {
    unsigned u = __float_as_uint(f);
    unsigned r = (u + 0x7fffu + ((u >> 16) & 1u)) >> 16;   // RNE
    return (unsigned short)r;
}

// ---------------------------------------------------------------------------
// Kernel A (MFMA): im2col GEMM conv (9->27ch, pad 1) + fp16 quantize +
// softmax + f32 outputs + 64B/px packed record (aff*w9 premult, bias folded).
// Block = 256 threads; 192 pixels of one image row (tid<192 own a pixel).
// Round-12 version, bit-exact.
// ---------------------------------------------------------------------------
__global__ __launch_bounds__(256) void conv_mfma_kernel(
    const float* __restrict__ g,          // [B,9,H,W]
    const float* __restrict__ cw,         // [27,9,3,3] == [27][81]
    const float* __restrict__ cb,         // [27]
    const float* __restrict__ confidence, // [B,1,H,W]
    const float* __restrict__ feat_fix,   // [B,1,H,W]
    const float* __restrict__ w9,         // [9]
    const float* __restrict__ biasp,      // [1]
    float* __restrict__ out_off,          // [B,18,H,W]
    float* __restrict__ out_aff,          // [B,9,H,W]
    uint4* __restrict__ packed)           // [NPIX][4] or nullptr
{
    __shared__ char lds[LDS_BYTES];

    const int tid = threadIdx.x;
    const int bid = blockIdx.x;
    const int seg = bid % NSEGC;
    const int y   = (bid / NSEGC) % HH;
    const int b   = bid / (NSEGC * HH);
    const int xs  = seg * SEGW;
    const int x   = xs + tid;

    // ---- stage B^T: Blds[n][k] = bf16(cw[n*81+k]), zero-padded to 32x96 ----
    for (int i = tid; i < 32 * 48; i += 256) {
        int n = i / 48;
        int kp = i - n * 48;
        unsigned v = 0;
        if (n < 27) {
            const float* wrow = cw + n * 81;
            int k0 = kp * 2;
            unsigned short h0 = (k0 < 81) ? f2bf(wrow[k0]) : (unsigned short)0;
            unsigned short h1 = (k0 + 1 < 81) ? f2bf(wrow[k0 + 1]) : (unsigned short)0;
            v = (unsigned)h0 | ((unsigned)h1 << 16);
        }
        *(unsigned*)(lds + B_OFF + n * AROW_B + kp * 4) = v;
    }

    // ---- build A row (im2col, 96 bf16 = 48 dwords in regs, static idx) ----
    if (tid < SEGW) {
        const float* gb = g + (size_t)b * 9 * HW;
        unsigned au[48];
#pragma unroll
        for (int j = 0; j < 48; ++j) au[j] = 0;
#pragma unroll
        for (int ci = 0; ci < 9; ++ci)
#pragma unroll
            for (int ty = 0; ty < 3; ++ty) {
                const int row = y + ty - 1;
                const bool vr = ((unsigned)row < HH);
                const float* rp = gb + (size_t)ci * HW + (size_t)(vr ? row : 0) * WW;
                const int cx = x - 1;
                float L = (vr && (unsigned)cx < WW) ? rp[cx] : 0.f;
                float M = (vr && (unsigned)(cx + 1) < WW) ? rp[cx + 1] : 0.f;
                float R = (vr && (unsigned)(cx + 2) < WW) ? rp[cx + 2] : 0.f;
                const int k = ci * 9 + ty * 3;
                au[(k) >> 1]     |= ((unsigned)f2bf(L)) << (((k) & 1) * 16);
                au[(k + 1) >> 1] |= ((unsigned)f2bf(M)) << (((k + 1) & 1) * 16);
                au[(k + 2) >> 1] |= ((unsigned)f2bf(R)) << (((k + 2) & 1) * 16);
            }
        char* arow = lds + tid * AROW_B;
#pragma unroll
        for (int j = 0; j < 12; ++j)
            *(uint4*)(arow + 16 * j) =
                make_uint4(au[4 * j], au[4 * j + 1], au[4 * j + 2], au[4 * j + 3]);
    }
    __syncthreads();

    // ---- MFMA: [192x96] x [96x32] -> [192x32], 18 mfma per wave ----
    const int w = tid >> 6, l = tid & 63;
    const int lrow = l & 15;
    const int lk = (l >> 4) * 8;
    f32x4 acc[3][2];
#pragma unroll
    for (int mt = 0; mt < 3; ++mt)
#pragma unroll
        for (int nt = 0; nt < 2; ++nt)
            acc[mt][nt] = (f32x4){0.f, 0.f, 0.f, 0.f};

#pragma unroll
    for (int kk = 0; kk < 3; ++kk) {
        const int ko = kk * 32 + lk;
        short8 bb0 = *(const short8*)(lds + B_OFF + lrow * AROW_B + ko * 2);
        short8 bb1 = *(const short8*)(lds + B_OFF + (lrow + 16) * AROW_B + ko * 2);
#pragma unroll
        for (int mt = 0; mt < 3; ++mt) {
            short8 aa = *(const short8*)(lds + (w * 48 + mt * 16 + lrow) * AROW_B + ko * 2);
            acc[mt][0] = __builtin_amdgcn_mfma_f32_16x16x32_bf16(aa, bb0, acc[mt][0], 0, 0, 0);
            acc[mt][1] = __builtin_amdgcn_mfma_f32_16x16x32_bf16(aa, bb1, acc[mt][1], 0, 0, 0);
        }
    }
    __syncthreads();   // done reading A; reuse region as OA[192][38] f32

    // scatter C: lane l holds D[row=(l>>4)*4+reg][col=l&15]
#pragma unroll
    for (int mt = 0; mt < 3; ++mt)
#pragma unroll
        for (int nt = 0; nt < 2; ++nt)
#pragma unroll
            for (int reg = 0; reg < 4; ++reg) {
                int px = w * 48 + mt * 16 + (l >> 4) * 4 + reg;
                int ch = nt * 16 + lrow;
                *(float*)(lds + px * OAROW_B + ch * 4) = acc[mt][nt][reg];
            }
    __syncthreads();

    // ---- epilogue (per pixel) ----
    if (tid >= SEGW || x >= WW) return;
    const int r = y * WW + x;
    const int p = b * HW + r;

    float oa[27];
    {
        const char* orow = lds + tid * OAROW_B;
#pragma unroll
        for (int j = 0; j < 13; ++j) {
            float2 v = *(const float2*)(orow + 8 * j);
            oa[2 * j] = v.x;
            if (2 * j + 1 < 27) oa[2 * j + 1] = v.y;
        }
        oa[26] = *(const float*)(orow + 26 * 4);
#pragma unroll
        for (int c = 0; c < 27; ++c) oa[c] += cb[c];
    }

    __half h[27];
#pragma unroll
    for (int c = 0; c < 18; ++c) h[c] = __float2half(oa[c]);

    float m = oa[18];
#pragma unroll
    for (int c = 19; c < 27; ++c) m = fmaxf(m, oa[c]);
    float e[9], s = 0.f;
#pragma unroll
    for (int k = 0; k < 9; ++k) { e[k] = expf(oa[18 + k] - m); s += e[k]; }
    float inv = 1.f / s;
#pragma unroll
    for (int k = 0; k < 9; ++k) h[18 + k] = __float2half(e[k] * inv);

#pragma unroll
    for (int c = 0; c < 18; ++c)
        out_off[(size_t)b * 18 * HW + (size_t)c * HW + r] = __half2float(h[c]);
#pragma unroll
    for (int k = 0; k < 9; ++k)
        out_aff[(size_t)b * 9 * HW + (size_t)k * HW + r] = __half2float(h[18 + k]);

    if (packed) {
        float cf = confidence[p];
        float ff = feat_fix[p];
        float sg = (ff > 0.f) ? 1.f : ((ff < 0.f) ? -1.f : 0.f);
        float conf = sg / (1.f + expf(-cf));
        float cm1 = 1.f - conf;
        float bias = biasp[0];

        // aff * w9 premultiplied (prop uses a single fma per tap)
        __half hw[9];
#pragma unroll
        for (int k = 0; k < 9; ++k)
            hw[k] = __float2half(__half2float(h[18 + k]) * w9[k]);

        unsigned uu[16];
#pragma unroll
        for (int i = 0; i < 9; ++i)
            uu[i] = (unsigned)__half_as_ushort(h[2 * i]) |
                    ((unsigned)__half_as_ushort(h[2 * i + 1]) << 16);
#pragma unroll
        for (int j = 0; j < 4; ++j)
            uu[9 + j] = (unsigned)__half_as_ushort(hw[2 * j]) |
                        ((unsigned)__half_as_ushort(hw[2 * j + 1]) << 16);
        uu[13] = (unsigned)__half_as_ushort(hw[8]);
        uu[14] = __float_as_uint(cm1);
        uu[15] = __float_as_uint(fmaf(cm1, bias, conf * ff));  // cff2

        uint4* dst = packed + (size_t)p * 4;
        dst[0] = make_uint4(uu[0], uu[1], uu[2], uu[3]);
        dst[1] = make_uint4(uu[4], uu[5], uu[6], uu[7]);
        dst[2] = make_uint4(uu[8], uu[9], uu[10], uu[11]);
        dst[3] = make_uint4(uu[12], uu[13], uu[14], uu[15]);
    }
}

// ---------------------------------------------------------------------------
// Kernel B (packed + 4-row LDS tile): one propagation step.
// Software-pipelined: row ty+1's 64B packed record is loaded at the top of
// iteration ty and consumed only after the 9-tap compute (hides L3 latency).
// ---------------------------------------------------------------------------
__global__ __launch_bounds__(256) void prop4_kernel(
    const float* __restrict__ src,
    float* __restrict__ dst,
    const uint4* __restrict__ packed,
    float* __restrict__ out_pred)
{
    __shared__ float tile[TROWS * TCOLS];

    const int xs = blockIdx.x * SEG;
    const int y0 = blockIdx.y * PROWS;
    const int b  = blockIdx.z;
    const float* sf = src + (size_t)b * HW;

    for (int i = threadIdx.x; i < TROWS * TCOLS; i += 256) {
        int rr = i / TCOLS;
        int cc = i - rr * TCOLS;
        int gy = y0 - YHALO + rr;
        int gx = xs - XHALO + cc;
        float v = 0.f;
        if ((unsigned)gy < HH && (unsigned)gx < WW)
            v = sf[(size_t)gy * WW + gx];
        tile[i] = v;
    }
    __syncthreads();

    const int x = xs + threadIdx.x;
    if (x >= WW) return;

    const int p0 = b * HW + y0 * WW + x;
    const uint4* pkbase = packed + (size_t)p0 * 4;

    // prologue: load row 0's record
    uint4 q0 = pkbase[0], q1 = pkbase[1], q2 = pkbase[2], q3 = pkbase[3];

#pragma unroll 1
    for (int ty = 0; ty < PROWS; ++ty) {
        // issue next row's record load now; consume after the tap loop
        const int nty = (ty + 1 < PROWS) ? (ty + 1) : ty;
        const uint4* nx = pkbase + (size_t)nty * WW * 4;
        uint4 n0 = nx[0], n1 = nx[1], n2 = nx[2], n3 = nx[3];

        const int y = y0 + ty;
        const int p = p0 + ty * WW;

        unsigned uu[14] = {q0.x, q0.y, q0.z, q0.w, q1.x, q1.y, q1.z, q1.w,
                           q2.x, q2.y, q2.z, q2.w, q3.x, q3.y};
        float hv[27];
#pragma unroll
        for (int i = 0; i < 13; ++i) {
            hv[2 * i]     = __half2float(__ushort_as_half((unsigned short)(uu[i] & 0xffff)));
            hv[2 * i + 1] = __half2float(__ushort_as_half((unsigned short)(uu[i] >> 16)));
        }
        hv[26] = __half2float(__ushort_as_half((unsigned short)(uu[13] & 0xffff)));
        const float cm1 = __uint_as_float(q3.z);
        const float cff = __uint_as_float(q3.w);

        float acc = 0.f;
#pragma unroll
        for (int k = 0; k < 9; ++k) {
            float py  = (float)(y + k / 3 - 1) + hv[2 * k];
            float pxx = (float)(x + k % 3 - 1) + hv[2 * k + 1];
            float y0f = floorf(py), x0f = floorf(pxx);
            float tyf = py - y0f, txf = pxx - x0f;
            int iy = (int)y0f, ix = (int)x0f;

            int ly = iy - y0 + YHALO;
            int lx = ix - xs + XHALO;
            float v00, v01, v10, v11;
            if ((unsigned)ly < (TROWS - 1) && (unsigned)lx < (TCOLS - 1)) {
                const float* t0 = &tile[ly * TCOLS + lx];
                v00 = t0[0];     v01 = t0[1];
                v10 = t0[TCOLS]; v11 = t0[TCOLS + 1];
            } else {
                bool vy0 = ((unsigned)iy < HH), vy1 = ((unsigned)(iy + 1) < HH);
                bool vx0 = ((unsigned)ix < WW), vx1 = ((unsigned)(ix + 1) < WW);
                v00 = (vy0 && vx0) ? sf[(size_t)iy * WW + ix] : 0.f;
                v01 = (vy0 && vx1) ? sf[(size_t)iy * WW + ix + 1] : 0.f;
                v10 = (vy1 && vx0) ? sf[(size_t)(iy + 1) * WW + ix] : 0.f;
                v11 = (vy1 && vx1) ? sf[(size_t)(iy + 1) * WW + ix + 1] : 0.f;
            }
            float top = fmaf(txf, v01 - v00, v00);
            float bot = fmaf(txf, v11 - v10, v10);
            float sv  = fmaf(tyf, bot - top, top);
            acc = fmaf(sv, hv[18 + k], acc);   // aff*w9 premultiplied
        }
        float fr = fmaf(cm1, acc, cff);        // bias folded into cff

        dst[p] = fr;
        if (out_pred) out_pred[p] = fr;

        // consume preloaded record (waitcnt lands here, after the tap loop)
        q0 = n0; q1 = n1; q2 = n2; q3 = n3;
    }
}

// ---------------------------------------------------------------------------
// Fallback (no ws): per-iteration kernel reading f32 off/aff planes.
// ---------------------------------------------------------------------------
__global__ __launch_bounds__(256) void prop_kernel(
    const float* __restrict__ src,
    float* __restrict__ dst,
    const float* __restrict__ off,
    const float* __restrict__ aff,
    const float* __restrict__ confidence,
    const float* __restrict__ feat_fix,
    const float* __restrict__ w9,
    const float* __restrict__ biasp,
    float* __restrict__ out_pred)
{
    int p = blockIdx.x * 256 + threadIdx.x;
    if (p >= NPIX) return;
    int b = p / HW;
    int r = p - b * HW;
    int y = r / WW;
    int x = r - y * WW;

    const float* offb = off + (size_t)b * 18 * HW + r;
    const float* affb = aff + (size_t)b * 9 * HW + r;
    const float* sf = src + (size_t)b * HW;

    float acc = 0.f;
#pragma unroll
    for (int k = 0; k < 9; ++k) {
        float dy = offb[(size_t)(2 * k) * HW];
        float dx = offb[(size_t)(2 * k + 1) * HW];
        float af = affb[(size_t)k * HW];
        float py = (float)y + (float)(k / 3 - 1) + dy;
        float px = (float)x + (float)(k % 3 - 1) + dx;
        float y0f = floorf(py), x0f = floorf(px);
        float ty = py - y0f, tx = px - x0f;
        int iy = (int)y0f, ix = (int)x0f;
        bool vy0 = ((unsigned)iy < HH), vy1 = ((unsigned)(iy + 1) < HH);
        bool vx0 = ((unsigned)ix < WW), vx1 = ((unsigned)(ix + 1) < WW);
        float v00 = (vy0 && vx0) ? sf[(size_t)iy * WW + ix] : 0.f;
        float v01 = (vy0 && vx1) ? sf[(size_t)iy * WW + ix + 1] : 0.f;
        float v10 = (vy1 && vx0) ? sf[(size_t)(iy + 1) * WW + ix] : 0.f;
        float v11 = (vy1 && vx1) ? sf[(size_t)(iy + 1) * WW + ix + 1] : 0.f;
        float top = (1.f - tx) * v00 + tx * v01;
        float bot = (1.f - tx) * v10 + tx * v11;
        float sv = (1.f - ty) * top + ty * bot;
        acc = fmaf(sv * af, w9[k], acc);
    }
    float dc = acc + biasp[0];

    float cf = confidence[p];
    float ffv = feat_fix[p];
    float sg = (ffv > 0.f) ? 1.f : ((ffv < 0.f) ? -1.f : 0.f);
    float conf = sg / (1.f + expf(-cf));
    float fr = (1.f - conf) * dc + conf * ffv;

    dst[p] = fr;
    if (out_pred) out_pred[p] = fr;
}

// ---------------------------------------------------------------------------
extern "C" void kernel_launch(void* const* d_in, const int* in_sizes, int n_in,
                              void* d_out, int out_size, void* d_ws, size_t ws_size,
                              hipStream_t stream) {
    const float* feat_init  = (const float*)d_in[0];
    const float* guidance   = (const float*)d_in[1];
    const float* confidence = (const float*)d_in[2];
    const float* feat_fix   = (const float*)d_in[3];
    const float* conv_w     = (const float*)d_in[4];
    const float* conv_b     = (const float*)d_in[5];
    const float* w          = (const float*)d_in[6];
    const float* bias       = (const float*)d_in[7];

    float* outf = (float*)d_out;
    float* out_pred = outf;                         // [B,1,H,W]
    float* out_list = outf + (size_t)NPIX;          // [18,B,1,H,W]
    float* out_off  = outf + (size_t)19 * NPIX;     // [B,18,H,W]
    float* out_aff  = outf + (size_t)37 * NPIX;     // [B,9,H,W]

    bool use_pack = (ws_size >= PACK_BYTES);
    uint4* packed = use_pack ? (uint4*)d_ws : nullptr;

    conv_mfma_kernel<<<NSEGC * HH * 2, 256, 0, stream>>>(
        guidance, conv_w, conv_b, confidence, feat_fix, w, bias,
        out_off, out_aff, packed);

    dim3 pgrid(NSEG, HH / PROWS, 2);
    int blocks = (NPIX + 255) / 256;
    const float* src = feat_init;
    for (int it = 0; it < NITER; ++it) {
        float* dstf = out_list + (size_t)it * NPIX;
        float* predp = (it == NITER - 1) ? out_pred : nullptr;
        if (use_pack) {
            prop4_kernel<<<pgrid, 256, 0, stream>>>(src, dstf, packed, predp);
        } else {
            prop_kernel<<<blocks, 256, 0, stream>>>(
                src, dstf, out_off, out_aff, confidence, feat_fix, w, bias, predp);
        }
        src = dstf;
    }
}

// Round 18
// 359.694 us; speedup vs baseline: 1.1063x; 1.1063x over previous
//
#include <hip/hip_runtime.h>
#include <hip/hip_fp16.h>

#define HH 352
#define WW 1216
#define HW (HH*WW)
#define NPIX (2*HW)      // 856064
#define NITER 18
#define PACK_BYTES ((size_t)NPIX * 64)

// conv MFMA geometry: 192-px tile, 3 blocks/CU  (round-12/16 verified: 93 us)
#define SEGW 192
#define NSEGC ((WW + SEGW - 1) / SEGW)    // 7
#define AROW_B 208                        // 104 bf16 per A row (96 used)
#define A_BYTES (SEGW * AROW_B)           // 39936
#define B_OFF A_BYTES
#define LDS_BYTES (A_BYTES + 32 * AROW_B) // 46592 -> 3 blocks/CU
#define OAROW_B 152                       // 38 f32 per OA row (27 used)

// prop LDS tile geometry: 4 rows x 256 cols per block (round-16 verified)
#define SEG 256
#define XHALO 6
#define YHALO 4
#define PROWS 4
#define TROWS (PROWS + 9)        // 13
#define TCOLS (SEG + 2*XHALO)    // 268
#define NSEG ((WW + SEG - 1) / SEG)   // 5

typedef __attribute__((ext_vector_type(8))) short short8;
typedef __attribute__((ext_vector_type(4))) float f32x4;

// manual RNE f32->bf16 twiddle: independent ALU work that overlaps load
// latency (round-15 lesson: intrinsic cast path was -40% despite fewer instrs)
__device__ __forceinline__ unsigned short f2bf(float f) {
    unsigned u = __float_as_uint(f);
    unsigned r = (u + 0x7fffu + ((u >> 16) & 1u)) >> 16;   // RNE
    return (unsigned short)r;
}

// ---------------------------------------------------------------------------
// Kernel A (MFMA): im2col GEMM conv (9->27ch, pad 1) + fp16 quantize +
// softmax + f32 outputs + 64B/px packed record (aff*w9 premult, bias folded).
// Block = 256 threads; 192 pixels of one image row (tid<192 own a pixel).
// ---------------------------------------------------------------------------
__global__ __launch_bounds__(256) void conv_mfma_kernel(
    const float* __restrict__ g,          // [B,9,H,W]
    const float* __restrict__ cw,         // [27,9,3,3] == [27][81]
    const float* __restrict__ cb,         // [27]
    const float* __restrict__ confidence, // [B,1,H,W]
    const float* __restrict__ feat_fix,   // [B,1,H,W]
    const float* __restrict__ w9,         // [9]
    const float* __restrict__ biasp,      // [1]
    float* __restrict__ out_off,          // [B,18,H,W]
    float* __restrict__ out_aff,          // [B,9,H,W]
    uint4* __restrict__ packed)           // [NPIX][4] or nullptr
{
    __shared__ char lds[LDS_BYTES];

    const int tid = threadIdx.x;
    const int bid = blockIdx.x;
    const int seg = bid % NSEGC;
    const int y   = (bid / NSEGC) % HH;
    const int b   = bid / (NSEGC * HH);
    const int xs  = seg * SEGW;
    const int x   = xs + tid;

    // ---- stage B^T: Blds[n][k] = bf16(cw[n*81+k]), zero-padded to 32x96 ----
    for (int i = tid; i < 32 * 48; i += 256) {
        int n = i / 48;
        int kp = i - n * 48;
        unsigned v = 0;
        if (n < 27) {
            const float* wrow = cw + n * 81;
            int k0 = kp * 2;
            unsigned short h0 = (k0 < 81) ? f2bf(wrow[k0]) : (unsigned short)0;
            unsigned short h1 = (k0 + 1 < 81) ? f2bf(wrow[k0 + 1]) : (unsigned short)0;
            v = (unsigned)h0 | ((unsigned)h1 << 16);
        }
        *(unsigned*)(lds + B_OFF + n * AROW_B + kp * 4) = v;
    }

    // ---- build A row (im2col, 96 bf16 = 48 dwords in regs, static idx) ----
    if (tid < SEGW) {
        const float* gb = g + (size_t)b * 9 * HW;
        unsigned au[48];
#pragma unroll
        for (int j = 0; j < 48; ++j) au[j] = 0;
#pragma unroll
        for (int ci = 0; ci < 9; ++ci)
#pragma unroll
            for (int ty = 0; ty < 3; ++ty) {
                const int row = y + ty - 1;
                const bool vr = ((unsigned)row < HH);
                const float* rp = gb + (size_t)ci * HW + (size_t)(vr ? row : 0) * WW;
                const int cx = x - 1;
                float L = (vr && (unsigned)cx < WW) ? rp[cx] : 0.f;
                float M = (vr && (unsigned)(cx + 1) < WW) ? rp[cx + 1] : 0.f;
                float R = (vr && (unsigned)(cx + 2) < WW) ? rp[cx + 2] : 0.f;
                const int k = ci * 9 + ty * 3;
                au[(k) >> 1]     |= ((unsigned)f2bf(L)) << (((k) & 1) * 16);
                au[(k + 1) >> 1] |= ((unsigned)f2bf(M)) << (((k + 1) & 1) * 16);
                au[(k + 2) >> 1] |= ((unsigned)f2bf(R)) << (((k + 2) & 1) * 16);
            }
        char* arow = lds + tid * AROW_B;
#pragma unroll
        for (int j = 0; j < 12; ++j)
            *(uint4*)(arow + 16 * j) =
                make_uint4(au[4 * j], au[4 * j + 1], au[4 * j + 2], au[4 * j + 3]);
    }
    __syncthreads();

    // ---- MFMA: [192x96] x [96x32] -> [192x32], 18 mfma per wave ----
    const int w = tid >> 6, l = tid & 63;
    const int lrow = l & 15;
    const int lk = (l >> 4) * 8;
    f32x4 acc[3][2];
#pragma unroll
    for (int mt = 0; mt < 3; ++mt)
#pragma unroll
        for (int nt = 0; nt < 2; ++nt)
            acc[mt][nt] = (f32x4){0.f, 0.f, 0.f, 0.f};

#pragma unroll
    for (int kk = 0; kk < 3; ++kk) {
        const int ko = kk * 32 + lk;
        short8 bb0 = *(const short8*)(lds + B_OFF + lrow * AROW_B + ko * 2);
        short8 bb1 = *(const short8*)(lds + B_OFF + (lrow + 16) * AROW_B + ko * 2);
#pragma unroll
        for (int mt = 0; mt < 3; ++mt) {
            short8 aa = *(const short8*)(lds + (w * 48 + mt * 16 + lrow) * AROW_B + ko * 2);
            acc[mt][0] = __builtin_amdgcn_mfma_f32_16x16x32_bf16(aa, bb0, acc[mt][0], 0, 0, 0);
            acc[mt][1] = __builtin_amdgcn_mfma_f32_16x16x32_bf16(aa, bb1, acc[mt][1], 0, 0, 0);
        }
    }
    __syncthreads();   // done reading A; reuse region as OA[192][38] f32

    // scatter C: lane l holds D[row=(l>>4)*4+reg][col=l&15]
#pragma unroll
    for (int mt = 0; mt < 3; ++mt)
#pragma unroll
        for (int nt = 0; nt < 2; ++nt)
#pragma unroll
            for (int reg = 0; reg < 4; ++reg) {
                int px = w * 48 + mt * 16 + (l >> 4) * 4 + reg;
                int ch = nt * 16 + lrow;
                *(float*)(lds + px * OAROW_B + ch * 4) = acc[mt][nt][reg];
            }
    __syncthreads();

    // ---- epilogue (per pixel) ----
    if (tid >= SEGW || x >= WW) return;
    const int r = y * WW + x;
    const int p = b * HW + r;

    float oa[27];
    {
        const char* orow = lds + tid * OAROW_B;
#pragma unroll
        for (int j = 0; j < 13; ++j) {
            float2 v = *(const float2*)(orow + 8 * j);
            oa[2 * j] = v.x;
            if (2 * j + 1 < 27) oa[2 * j + 1] = v.y;
        }
        oa[26] = *(const float*)(orow + 26 * 4);
#pragma unroll
        for (int c = 0; c < 27; ++c) oa[c] += cb[c];
    }

    __half h[27];
#pragma unroll
    for (int c = 0; c < 18; ++c) h[c] = __float2half(oa[c]);

    float m = oa[18];
#pragma unroll
    for (int c = 19; c < 27; ++c) m = fmaxf(m, oa[c]);
    float e[9], s = 0.f;
#pragma unroll
    for (int k = 0; k < 9; ++k) { e[k] = expf(oa[18 + k] - m); s += e[k]; }
    float inv = 1.f / s;
#pragma unroll
    for (int k = 0; k < 9; ++k) h[18 + k] = __float2half(e[k] * inv);

#pragma unroll
    for (int c = 0; c < 18; ++c)
        out_off[(size_t)b * 18 * HW + (size_t)c * HW + r] = __half2float(h[c]);
#pragma unroll
    for (int k = 0; k < 9; ++k)
        out_aff[(size_t)b * 9 * HW + (size_t)k * HW + r] = __half2float(h[18 + k]);

    if (packed) {
        float cf = confidence[p];
        float ff = feat_fix[p];
        float sg = (ff > 0.f) ? 1.f : ((ff < 0.f) ? -1.f : 0.f);
        float conf = sg / (1.f + expf(-cf));
        float cm1 = 1.f - conf;
        float bias = biasp[0];

        // aff * w9 premultiplied (prop uses a single fma per tap)
        __half hw[9];
#pragma unroll
        for (int k = 0; k < 9; ++k)
            hw[k] = __float2half(__half2float(h[18 + k]) * w9[k]);

        unsigned uu[16];
#pragma unroll
        for (int i = 0; i < 9; ++i)
            uu[i] = (unsigned)__half_as_ushort(h[2 * i]) |
                    ((unsigned)__half_as_ushort(h[2 * i + 1]) << 16);
#pragma unroll
        for (int j = 0; j < 4; ++j)
            uu[9 + j] = (unsigned)__half_as_ushort(hw[2 * j]) |
                        ((unsigned)__half_as_ushort(hw[2 * j + 1]) << 16);
        uu[13] = (unsigned)__half_as_ushort(hw[8]);
        uu[14] = __float_as_uint(cm1);
        uu[15] = __float_as_uint(fmaf(cm1, bias, conf * ff));  // cff2

        uint4* dst = packed + (size_t)p * 4;
        dst[0] = make_uint4(uu[0], uu[1], uu[2], uu[3]);
        dst[1] = make_uint4(uu[4], uu[5], uu[6], uu[7]);
        dst[2] = make_uint4(uu[8], uu[9], uu[10], uu[11]);
        dst[3] = make_uint4(uu[12], uu[13], uu[14], uu[15]);
    }
}

// ---------------------------------------------------------------------------
// Kernel B (packed + 4-row LDS tile): one propagation step (round-16 best;
// round-17 lesson: do NOT hand-pipeline the packed loads — TLP covers them).
// ---------------------------------------------------------------------------
__global__ __launch_bounds__(256) void prop4_kernel(
    const float* __restrict__ src,
    float* __restrict__ dst,
    const uint4* __restrict__ packed,
    float* __restrict__ out_pred)
{
    __shared__ float tile[TROWS * TCOLS];

    const int xs = blockIdx.x * SEG;
    const int y0 = blockIdx.y * PROWS;
    const int b  = blockIdx.z;
    const float* sf = src + (size_t)b * HW;

    for (int i = threadIdx.x; i < TROWS * TCOLS; i += 256) {
        int rr = i / TCOLS;
        int cc = i - rr * TCOLS;
        int gy = y0 - YHALO + rr;
        int gx = xs - XHALO + cc;
        float v = 0.f;
        if ((unsigned)gy < HH && (unsigned)gx < WW)
            v = sf[(size_t)gy * WW + gx];
        tile[i] = v;
    }
    __syncthreads();

    const int x = xs + threadIdx.x;
    if (x >= WW) return;

#pragma unroll 1
    for (int ty = 0; ty < PROWS; ++ty) {
        const int y = y0 + ty;
        const int p = b * HW + y * WW + x;

        const uint4* pk = packed + (size_t)p * 4;   // plain loads (L3-resident)
        uint4 q0 = pk[0], q1 = pk[1], q2 = pk[2], q3 = pk[3];
        unsigned uu[14] = {q0.x, q0.y, q0.z, q0.w, q1.x, q1.y, q1.z, q1.w,
                           q2.x, q2.y, q2.z, q2.w, q3.x, q3.y};
        float hv[27];
#pragma unroll
        for (int i = 0; i < 13; ++i) {
            hv[2 * i]     = __half2float(__ushort_as_half((unsigned short)(uu[i] & 0xffff)));
            hv[2 * i + 1] = __half2float(__ushort_as_half((unsigned short)(uu[i] >> 16)));
        }
        hv[26] = __half2float(__ushort_as_half((unsigned short)(uu[13] & 0xffff)));
        const float cm1 = __uint_as_float(q3.z);
        const float cff = __uint_as_float(q3.w);

        float acc = 0.f;
#pragma unroll
        for (int k = 0; k < 9; ++k) {
            float py  = (float)(y + k / 3 - 1) + hv[2 * k];
            float pxx = (float)(x + k % 3 - 1) + hv[2 * k + 1];
            float y0f = floorf(py), x0f = floorf(pxx);
            float tyf = py - y0f, txf = pxx - x0f;
            int iy = (int)y0f, ix = (int)x0f;

            int ly = iy - y0 + YHALO;
            int lx = ix - xs + XHALO;
            float v00, v01, v10, v11;
            if ((unsigned)ly < (TROWS - 1) && (unsigned)lx < (TCOLS - 1)) {
                const float* t0 = &tile[ly * TCOLS + lx];
                v00 = t0[0];     v01 = t0[1];
                v10 = t0[TCOLS]; v11 = t0[TCOLS + 1];
            } else {
                bool vy0 = ((unsigned)iy < HH), vy1 = ((unsigned)(iy + 1) < HH);
                bool vx0 = ((unsigned)ix < WW), vx1 = ((unsigned)(ix + 1) < WW);
                v00 = (vy0 && vx0) ? sf[(size_t)iy * WW + ix] : 0.f;
                v01 = (vy0 && vx1) ? sf[(size_t)iy * WW + ix + 1] : 0.f;
                v10 = (vy1 && vx0) ? sf[(size_t)(iy + 1) * WW + ix] : 0.f;
                v11 = (vy1 && vx1) ? sf[(size_t)(iy + 1) * WW + ix + 1] : 0.f;
            }
            float top = fmaf(txf, v01 - v00, v00);
            float bot = fmaf(txf, v11 - v10, v10);
            float sv  = fmaf(tyf, bot - top, top);
            acc = fmaf(sv, hv[18 + k], acc);   // aff*w9 premultiplied
        }
        float fr = fmaf(cm1, acc, cff);        // bias folded into cff

        dst[p] = fr;
        if (out_pred) out_pred[p] = fr;
    }
}

// ---------------------------------------------------------------------------
// Fallback (no ws): per-iteration kernel reading f32 off/aff planes.
// ---------------------------------------------------------------------------
__global__ __launch_bounds__(256) void prop_kernel(
    const float* __restrict__ src,
    float* __restrict__ dst,
    const float* __restrict__ off,
    const float* __restrict__ aff,
    const float* __restrict__ confidence,
    const float* __restrict__ feat_fix,
    const float* __restrict__ w9,
    const float* __restrict__ biasp,
    float* __restrict__ out_pred)
{
    int p = blockIdx.x * 256 + threadIdx.x;
    if (p >= NPIX) return;
    int b = p / HW;
    int r = p - b * HW;
    int y = r / WW;
    int x = r - y * WW;

    const float* offb = off + (size_t)b * 18 * HW + r;
    const float* affb = aff + (size_t)b * 9 * HW + r;
    const float* sf = src + (size_t)b * HW;

    float acc = 0.f;
#pragma unroll
    for (int k = 0; k < 9; ++k) {
        float dy = offb[(size_t)(2 * k) * HW];
        float dx = offb[(size_t)(2 * k + 1) * HW];
        float af = affb[(size_t)k * HW];
        float py = (float)y + (float)(k / 3 - 1) + dy;
        float px = (float)x + (float)(k % 3 - 1) + dx;
        float y0f = floorf(py), x0f = floorf(px);
        float ty = py - y0f, tx = px - x0f;
        int iy = (int)y0f, ix = (int)x0f;
        bool vy0 = ((unsigned)iy < HH), vy1 = ((unsigned)(iy + 1) < HH);
        bool vx0 = ((unsigned)ix < WW), vx1 = ((unsigned)(ix + 1) < WW);
        float v00 = (vy0 && vx0) ? sf[(size_t)iy * WW + ix] : 0.f;
        float v01 = (vy0 && vx1) ? sf[(size_t)iy * WW + ix + 1] : 0.f;
        float v10 = (vy1 && vx0) ? sf[(size_t)(iy + 1) * WW + ix] : 0.f;
        float v11 = (vy1 && vx1) ? sf[(size_t)(iy + 1) * WW + ix + 1] : 0.f;
        float top = (1.f - tx) * v00 + tx * v01;
        float bot = (1.f - tx) * v10 + tx * v11;
        float sv = (1.f - ty) * top + ty * bot;
        acc = fmaf(sv * af, w9[k], acc);
    }
    float dc = acc + biasp[0];

    float cf = confidence[p];
    float ffv = feat_fix[p];
    float sg = (ffv > 0.f) ? 1.f : ((ffv < 0.f) ? -1.f : 0.f);
    float conf = sg / (1.f + expf(-cf));
    float fr = (1.f - conf) * dc + conf * ffv;

    dst[p] = fr;
    if (out_pred) out_pred[p] = fr;
}

// ---------------------------------------------------------------------------
extern "C" void kernel_launch(void* const* d_in, const int* in_sizes, int n_in,
                              void* d_out, int out_size, void* d_ws, size_t ws_size,
                              hipStream_t stream) {
    const float* feat_init  = (const float*)d_in[0];
    const float* guidance   = (const float*)d_in[1];
    const float* confidence = (const float*)d_in[2];
    const float* feat_fix   = (const float*)d_in[3];
    const float* conv_w     = (const float*)d_in[4];
    const float* conv_b     = (const float*)d_in[5];
    const float* w          = (const float*)d_in[6];
    const float* bias       = (const float*)d_in[7];

    float* outf = (float*)d_out;
    float* out_pred = outf;                         // [B,1,H,W]
    float* out_list = outf + (size_t)NPIX;          // [18,B,1,H,W]
    float* out_off  = outf + (size_t)19 * NPIX;     // [B,18,H,W]
    float* out_aff  = outf + (size_t)37 * NPIX;     // [B,9,H,W]

    bool use_pack = (ws_size >= PACK_BYTES);
    uint4* packed = use_pack ? (uint4*)d_ws : nullptr;

    conv_mfma_kernel<<<NSEGC * HH * 2, 256, 0, stream>>>(
        guidance, conv_w, conv_b, confidence, feat_fix, w, bias,
        out_off, out_aff, packed);

    dim3 pgrid(NSEG, HH / PROWS, 2);
    int blocks = (NPIX + 255) / 256;
    const float* src = feat_init;
    for (int it = 0; it < NITER; ++it) {
        float* dstf = out_list + (size_t)it * NPIX;
        float* predp = (it == NITER - 1) ? out_pred : nullptr;
        if (use_pack) {
            prop4_kernel<<<pgrid, 256, 0, stream>>>(src, dstf, packed, predp);
        } else {
            prop_kernel<<<blocks, 256, 0, stream>>>(
                src, dstf, out_off, out_aff, confidence, feat_fix, w, bias, predp);
        }
        src = dstf;
    }
}